// Round 4
// baseline (870.285 us; speedup 1.0000x reference)
//
#include <hip/hip_runtime.h>
#include <cstdint>
#include <cstddef>

#define DD   512
#define NTOK 32768
#define NE   8
#define BM   256
#define BN   256
#define BK   32
#define NT   (DD / BK)   // 16 k-steps
#define RBLK 1024

typedef unsigned int  u32;
typedef unsigned short u16;
typedef unsigned long long u64;
using bf16x8 = __attribute__((ext_vector_type(8))) short;
using f32x4  = __attribute__((ext_vector_type(4))) float;

// LDS layout (u16 units): double buffer of {Ah, Al, Bh, Bl}, each 256x32 u16 (16KB)
#define LDS_BUF 32768
#define OAH 0
#define OAL 8192
#define OBH 16384
#define OBL 24576

__device__ __forceinline__ u32 rne_bf16(float f) {
    u32 u = __float_as_uint(f);
    return (u + 0x7FFFu + ((u >> 16) & 1u)) >> 16;
}
__device__ __forceinline__ void split1(float f, u16& h, u16& l) {
    u32 hb = rne_bf16(f);
    float hf = __uint_as_float(hb << 16);
    float r = f - hf;
    u32 lb = rne_bf16(r);
    h = (u16)hb; l = (u16)lb;
}
__device__ __forceinline__ void split8(const float4& a, const float4& b,
                                       uint4& H, uint4& L) {
    float fs[8] = {a.x, a.y, a.z, a.w, b.x, b.y, b.z, b.w};
    u16 hs[8], ls[8];
#pragma unroll
    for (int i = 0; i < 8; i++) split1(fs[i], hs[i], ls[i]);
    H.x = hs[0] | ((u32)hs[1] << 16); H.y = hs[2] | ((u32)hs[3] << 16);
    H.z = hs[4] | ((u32)hs[5] << 16); H.w = hs[6] | ((u32)hs[7] << 16);
    L.x = ls[0] | ((u32)ls[1] << 16); L.y = ls[2] | ((u32)ls[3] << 16);
    L.z = ls[4] | ((u32)ls[5] << 16); L.w = ls[6] | ((u32)ls[7] << 16);
}

__device__ __forceinline__ void gl16(const void* src, const u16* ldsdst) {
    __builtin_amdgcn_global_load_lds(
        (const __attribute__((address_space(1))) u32*)src,
        (__attribute__((address_space(3))) u32*)(void*)ldsdst, 16, 0, 0);
}

// ---------------- routing: block-aggregated counts ----------------
__global__ __launch_bounds__(RBLK) void route_kernel(
    const float* __restrict__ x,
    const float* __restrict__ Wg,
    const float* __restrict__ bg,
    int t0, int T,
    int* __restrict__ counts,
    int* __restrict__ eids,
    float* __restrict__ wts) {
    __shared__ int lcnt[NE];
    int tid = threadIdx.x;
    if (tid < NE) lcnt[tid] = 0;
    __syncthreads();

    int i = blockIdx.x * RBLK + tid;
    bool active = (i < T);
    int e0 = 0, e1 = 0;
    if (active) {
        int n = t0 + i;
        const float* xr = x + (size_t)n * DD + (DD - 3);
        float x0 = xr[0], x1 = xr[1], x2 = xr[2];
        float g[NE];
#pragma unroll
        for (int e = 0; e < NE; e++)
            g[e] = x0 * Wg[e] + x1 * Wg[NE + e] + x2 * Wg[2 * NE + e] + bg[e];
        float v0 = g[0];
#pragma unroll
        for (int e = 1; e < NE; e++) if (g[e] > v0) { v0 = g[e]; e0 = e; }
        float v1 = -3.0e38f; e1 = -1;
#pragma unroll
        for (int e = 0; e < NE; e++) if (e != e0 && g[e] > v1) { v1 = g[e]; e1 = e; }
        float t = expf(v1 - v0);
        float s = 1.0f / (1.0f + t);
        eids[2 * i] = e0; eids[2 * i + 1] = e1;
        wts[2 * i] = s;  wts[2 * i + 1] = t * s;
    }

    int lane = tid & 63;
#pragma unroll
    for (int k = 0; k < 2; k++) {
        int e = active ? (k ? e1 : e0) : -1;
#pragma unroll
        for (int ex = 0; ex < NE; ex++) {
            u64 m = __ballot(e == ex);
            if (m && lane == 0) atomicAdd(&lcnt[ex], __popcll(m));
        }
    }
    __syncthreads();
    if (tid < NE && lcnt[tid]) atomicAdd(&counts[tid], lcnt[tid]);
}

// ---------------- padded prefix sum (pad to BM=256) ----------------
__global__ void offsets_kernel(const int* __restrict__ counts,
                               int* __restrict__ off,
                               int* __restrict__ cursor) {
    if (threadIdx.x == 0) {
        int acc = 0;
        for (int e = 0; e < NE; e++) {
            off[e] = acc;
            cursor[e] = acc;
            acc += (counts[e] + (BM - 1)) & ~(BM - 1);
        }
        off[NE] = acc;
    }
}

// ---------------- scatter: block/wave-aggregated ----------------
__global__ __launch_bounds__(RBLK) void scatter_kernel(
    int t0, int T,
    const int* __restrict__ eids,
    int* __restrict__ cursor,
    int* __restrict__ list_token,
    int* __restrict__ posl) {
    __shared__ int lcnt[NE], lbase[NE];
    __shared__ int woff[RBLK / 64][NE];
    int tid = threadIdx.x, lane = tid & 63, wv = tid >> 6;
    int i = blockIdx.x * RBLK + tid;
    bool active = (i < T);
    u64 lmask = (1ull << lane) - 1ull;

#pragma unroll
    for (int k = 0; k < 2; k++) {
        if (tid < NE) lcnt[tid] = 0;
        __syncthreads();
        int e = active ? eids[2 * i + k] : -1;
        u64 mymask = 0;
#pragma unroll
        for (int ex = 0; ex < NE; ex++) {
            u64 m = __ballot(e == ex);
            if (e == ex) mymask = m;
            if (m && lane == 0) woff[wv][ex] = atomicAdd(&lcnt[ex], __popcll(m));
        }
        __syncthreads();
        if (tid < NE) lbase[tid] = lcnt[tid] ? atomicAdd(&cursor[tid], lcnt[tid]) : 0;
        __syncthreads();
        if (active) {
            int p = lbase[e] + woff[wv][e] + __popcll(mymask & lmask);
            list_token[p] = t0 + i;
            posl[2 * i + k] = p;
        }
        __syncthreads();
    }
}

// ---------------- weight transpose + hi/lo split ----------------
__global__ void convert_w(const float* __restrict__ Wh,
                          const float* __restrict__ Wo,
                          u16* __restrict__ WtHi, u16* __restrict__ WtLo) {
    __shared__ float tile[32][33];
    int z = blockIdx.z;             // e*4 + l
    int e = z >> 2, l = z & 3;
    const float* src = (l < 3) ? (Wh + ((size_t)e * 3 + l) * DD * DD)
                               : (Wo + (size_t)e * DD * DD);
    int bx = blockIdx.x, by = blockIdx.y;
    int tx = threadIdx.x, ty = threadIdx.y; // 32 x 8
#pragma unroll
    for (int j = 0; j < 4; j++)
        tile[ty + j * 8][tx] = src[(size_t)(by * 32 + ty + j * 8) * DD + bx * 32 + tx];
    __syncthreads();
    u16* dh = WtHi + (size_t)z * DD * DD;
    u16* dl = WtLo + (size_t)z * DD * DD;
#pragma unroll
    for (int j = 0; j < 4; j++) {
        int n = bx * 32 + ty + j * 8;
        int k = by * 32 + tx;
        u16 h, lo;
        split1(tile[tx][ty + j * 8], h, lo);
        dh[(size_t)n * DD + k] = h;
        dl[(size_t)n * DD + k] = lo;
    }
}

// ---------------- split-bf16 MFMA GEMM, 256x256x32, 8 waves, 2-phase pipeline ----------------
template <bool GATHER, bool RELU, bool OUTF32>
__global__ __launch_bounds__(512, 2) void moe_gemm(
    const float* __restrict__ Xf,
    const u16* __restrict__ Ahi, const u16* __restrict__ Alo,
    const int* __restrict__ list_token,
    const u16* __restrict__ WtHi, const u16* __restrict__ WtLo,
    int layer,
    const float* __restrict__ bptr, int bestride,
    const int* __restrict__ off,
    u16* __restrict__ Chi, u16* __restrict__ Clo,
    float* __restrict__ Cf)
{
    int rb = blockIdx.x * BM;
    if (rb >= off[NE]) return;
    int e = 0;
#pragma unroll
    for (int q = 1; q < NE; q++) if (rb >= off[q]) e = q;
    int cb = blockIdx.y * BN;

    __shared__ u16 lds[2 * LDS_BUF];   // 128 KiB

    const int tid = threadIdx.x;
    const int lane = tid & 63, wv = tid >> 6;

    // ---- staging mapping: chunk c = 512*j + tid; row = c>>2, u = c&3 ----
    const int srow0 = tid >> 2;   // 0..127 (j=0); +128 for j=1
    const int su    = tid & 3;

    const size_t wbase = ((size_t)e * 4 + layer) * (size_t)DD * DD;

    const u16* aSrcH[2]; const u16* aSrcL[2];
    const u16* bSrcH[2]; const u16* bSrcL[2];
    const float* aSrcF[2];
    int tokrow[2] = {0, 0};
    int awdst[2]  = {0, 0};
#pragma unroll
    for (int j = 0; j < 2; j++) {
        int row = srow0 + 128 * j;
        int us  = su ^ ((row >> 1) & 3);       // pre-swizzled source unit
        if (!GATHER) {
            aSrcH[j] = Ahi + (size_t)(rb + row) * DD + us * 8;
            aSrcL[j] = Alo + (size_t)(rb + row) * DD + us * 8;
        } else {
            int r = list_token[rb + row];
            tokrow[j] = r;
            aSrcF[j]  = Xf + (size_t)(r < 0 ? 0 : r) * DD;
            awdst[j]  = row * 32 + us * 8;     // swizzled ds_write dest
        }
        bSrcH[j] = WtHi + wbase + (size_t)(cb + row) * DD + us * 8;
        bSrcL[j] = WtLo + wbase + (size_t)(cb + row) * DD + us * 8;
    }
    // wave-uniform LDS chunk bases (u16 idx)
    const int cbj[2] = { (64 * wv) * 8, (512 + 64 * wv) * 8 };

    // ---- MFMA read mapping ----
    const int r15 = lane & 15, lg = lane >> 4;
    const int wr = (wv >> 2) * 128, wc = (wv & 3) * 64;
    const int arow = wr + r15, brow = wc + r15;
    const u32 aoff = (u32)(arow * 32 + (lg ^ ((arow >> 1) & 3)) * 8);
    const u32 boff = (u32)(brow * 32 + (lg ^ ((brow >> 1) & 3)) * 8);

    f32x4 acc[8][4];
#pragma unroll
    for (int i = 0; i < 8; i++)
#pragma unroll
        for (int j = 0; j < 4; j++) acc[i][j] = (f32x4){0.f, 0.f, 0.f, 0.f};

#define STAGE_B(bb_, k0_)                                             \
    {                                                                 \
        _Pragma("unroll")                                             \
        for (int j = 0; j < 2; j++) {                                 \
            gl16(bSrcH[j] + (k0_), &lds[(bb_) + OBH + cbj[j]]);       \
            gl16(bSrcL[j] + (k0_), &lds[(bb_) + OBL + cbj[j]]);       \
        }                                                             \
    }
#define STAGE_A(bb_, k0_)                                             \
    {                                                                 \
        _Pragma("unroll")                                             \
        for (int j = 0; j < 2; j++) {                                 \
            gl16(aSrcH[j] + (k0_), &lds[(bb_) + OAH + cbj[j]]);       \
            gl16(aSrcL[j] + (k0_), &lds[(bb_) + OAL + cbj[j]]);       \
        }                                                             \
    }

    float4 fA[2][2];

    // prologue
    STAGE_B(0, 0);
    if (!GATHER) STAGE_A(0, 0);

    int bb = 0;
    for (int t = 0; t < NT; t++) {
        const int k0n = (t + 1) * BK;
        if (GATHER) {
            // issue A(t) f32 loads (oldest), then B(t+1) prefetch
#pragma unroll
            for (int j = 0; j < 2; j++) {
                const float4* fp = (const float4*)(aSrcF[j] + t * BK + su * 8);
                float4 v0 = fp[0], v1 = fp[1];
                if (tokrow[j] < 0) { v0 = make_float4(0,0,0,0); v1 = make_float4(0,0,0,0); }
                fA[j][0] = v0; fA[j][1] = v1;
            }
            if (t + 1 < NT) {
                STAGE_B(bb ^ LDS_BUF, k0n);
                asm volatile("s_waitcnt vmcnt(4)" ::: "memory");
            } else {
                asm volatile("s_waitcnt vmcnt(0)" ::: "memory");
            }
#pragma unroll
            for (int j = 0; j < 2; j++) {
                uint4 H, L;
                split8(fA[j][0], fA[j][1], H, L);
                *(uint4*)&lds[bb + OAH + awdst[j]] = H;
                *(uint4*)&lds[bb + OAL + awdst[j]] = L;
            }
            asm volatile("s_waitcnt lgkmcnt(0)" ::: "memory");
            __builtin_amdgcn_s_barrier();
        } else {
            if (t + 1 < NT) {
                STAGE_A(bb ^ LDS_BUF, k0n);
                STAGE_B(bb ^ LDS_BUF, k0n);
                asm volatile("s_waitcnt vmcnt(8)" ::: "memory");
            } else {
                asm volatile("s_waitcnt vmcnt(0)" ::: "memory");
            }
            __builtin_amdgcn_s_barrier();
        }

        // ---- compute on buf bb ----
        bf16x8 bhf[4], blf[4];
#pragma unroll
        for (int ni = 0; ni < 4; ni++) {
            bhf[ni] = *(const bf16x8*)&lds[bb + OBH + boff + ni * 512];
            blf[ni] = *(const bf16x8*)&lds[bb + OBL + boff + ni * 512];
        }
#pragma unroll
        for (int mi = 0; mi < 8; mi++) {
            bf16x8 ah = *(const bf16x8*)&lds[bb + OAH + aoff + mi * 512];
            bf16x8 al = *(const bf16x8*)&lds[bb + OAL + aoff + mi * 512];
#pragma unroll
            for (int ni = 0; ni < 4; ni++) {
                acc[mi][ni] = __builtin_amdgcn_mfma_f32_16x16x32_bf16(ah, bhf[ni], acc[mi][ni], 0, 0, 0);
                acc[mi][ni] = __builtin_amdgcn_mfma_f32_16x16x32_bf16(al, bhf[ni], acc[mi][ni], 0, 0, 0);
                acc[mi][ni] = __builtin_amdgcn_mfma_f32_16x16x32_bf16(ah, blf[ni], acc[mi][ni], 0, 0, 0);
            }
        }
        asm volatile("" ::: "memory");
        __builtin_amdgcn_s_barrier();
        bb ^= LDS_BUF;
    }
#undef STAGE_A
#undef STAGE_B

    // ---- epilogue ----
#pragma unroll
    for (int ni = 0; ni < 4; ni++) {
        int col = cb + wc + ni * 16 + r15;
        float bbias = bptr[e * bestride + col];
#pragma unroll
        for (int mi = 0; mi < 8; mi++) {
            int row0 = rb + wr + mi * 16 + lg * 4;
#pragma unroll
            for (int rr = 0; rr < 4; rr++) {
                float v = acc[mi][ni][rr] + bbias;
                if (RELU) v = fmaxf(v, 0.f);
                size_t idx = (size_t)(row0 + rr) * DD + col;
                if (OUTF32) {
                    Cf[idx] = v;
                } else {
                    u16 h, lo;
                    split1(v, h, lo);
                    Chi[idx] = h;
                    Clo[idx] = lo;
                }
            }
        }
    }
}

// ---------------- combine ----------------
__global__ void combine_kernel(int t0, int T,
                               const float* __restrict__ y,
                               const int* __restrict__ posl,
                               const float* __restrict__ wts,
                               float* __restrict__ out) {
    int idx = blockIdx.x * blockDim.x + threadIdx.x;
    if (idx >= T * (DD / 4)) return;
    int i = idx >> 7;
    int j = idx & 127;
    int p0 = posl[2 * i], p1 = posl[2 * i + 1];
    float w0 = wts[2 * i], w1 = wts[2 * i + 1];
    float4 a = ((const float4*)(y + (size_t)p0 * DD))[j];
    float4 b = ((const float4*)(y + (size_t)p1 * DD))[j];
    float4 c;
    c.x = w0 * a.x + w1 * b.x;
    c.y = w0 * a.y + w1 * b.y;
    c.z = w0 * a.z + w1 * b.z;
    c.w = w0 * a.w + w1 * b.w;
    ((float4*)(out + (size_t)(t0 + i) * DD))[j] = c;
}

extern "C" void kernel_launch(void* const* d_in, const int* in_sizes, int n_in,
                              void* d_out, int out_size, void* d_ws, size_t ws_size,
                              hipStream_t stream) {
    const float* x  = (const float*)d_in[0];
    const float* Wg = (const float*)d_in[1];
    const float* bg = (const float*)d_in[2];
    const float* Wh = (const float*)d_in[3];
    const float* bh = (const float*)d_in[4];
    const float* Wo = (const float*)d_in[5];
    const float* bo = (const float*)d_in[6];
    float* out = (float*)d_out;

    const size_t WT_ELEMS = (size_t)NE * 4 * DD * DD;
    int T = NTOK;
    while (T > 64) {
        size_t C = 2 * (size_t)T + NE * BM;
        size_t need = 4096 + 2 * WT_ELEMS * 2 + 3 * ((size_t)T * 2 * 4)
                    + C * 4 + 512 + 4 * (C * (size_t)DD * 2);
        if (need <= ws_size) break;
        T >>= 1;
    }
    int phases = (NTOK + T - 1) / T;
    size_t C = 2 * (size_t)T + NE * BM;

    char* p = (char*)d_ws;
    int* counts = (int*)p;
    int* off    = (int*)(p + 64);
    int* cursor = (int*)(p + 128);
    char* q = p + 4096;
    u16* WtHi = (u16*)q;  q += WT_ELEMS * 2;
    u16* WtLo = (u16*)q;  q += WT_ELEMS * 2;
    int* eids = (int*)q;  q += (size_t)T * 2 * 4;
    int* posl = (int*)q;  q += (size_t)T * 2 * 4;
    float* wts = (float*)q; q += (size_t)T * 2 * 4;
    int* list_token = (int*)q; q += C * 4;
    q = (char*)(((uintptr_t)q + 255) & ~(uintptr_t)255);
    u16* bufA_hi = (u16*)q; q += C * DD * 2;
    u16* bufA_lo = (u16*)q; q += C * DD * 2;
    u16* bufB_hi = (u16*)q; q += C * DD * 2;   // final fp32 y aliases hi+lo
    u16* bufB_lo = (u16*)q; q += C * DD * 2;
    float* yf = (float*)bufB_hi;

    convert_w<<<dim3(16, 16, 32), dim3(32, 8), 0, stream>>>(Wh, Wo, WtHi, WtLo);

    for (int ph = 0; ph < phases; ph++) {
        int t0 = ph * T;
        int Tc = (NTOK - t0 < T) ? (NTOK - t0) : T;

        hipMemsetAsync(counts, 0, 256, stream);
        hipMemsetAsync(list_token, 0xFF, C * 4, stream);

        route_kernel<<<(Tc + RBLK - 1) / RBLK, RBLK, 0, stream>>>(
            x, Wg, bg, t0, Tc, counts, eids, wts);
        offsets_kernel<<<1, 64, 0, stream>>>(counts, off, cursor);
        scatter_kernel<<<(Tc + RBLK - 1) / RBLK, RBLK, 0, stream>>>(
            t0, Tc, eids, cursor, list_token, posl);

        dim3 g((unsigned)(C / BM), DD / BN);
        moe_gemm<true, true, false><<<g, 512, 0, stream>>>(
            x, nullptr, nullptr, list_token, WtHi, WtLo, 0,
            bh, 3 * DD, off, bufA_hi, bufA_lo, nullptr);
        moe_gemm<false, true, false><<<g, 512, 0, stream>>>(
            nullptr, bufA_hi, bufA_lo, nullptr, WtHi, WtLo, 1,
            bh + DD, 3 * DD, off, bufB_hi, bufB_lo, nullptr);
        moe_gemm<false, true, false><<<g, 512, 0, stream>>>(
            nullptr, bufB_hi, bufB_lo, nullptr, WtHi, WtLo, 2,
            bh + 2 * DD, 3 * DD, off, bufA_hi, bufA_lo, nullptr);
        moe_gemm<false, false, true><<<g, 512, 0, stream>>>(
            nullptr, bufA_hi, bufA_lo, nullptr, WtHi, WtLo, 3,
            bo, DD, off, nullptr, nullptr, yf);

        combine_kernel<<<((size_t)Tc * (DD / 4) + 255) / 256, 256, 0, stream>>>(
            t0, Tc, yf, posl, wts, out);
    }
}

// Round 5
// 745.507 us; speedup vs baseline: 1.1674x; 1.1674x over previous
//
#include <hip/hip_runtime.h>
#include <cstdint>
#include <cstddef>

#define DD   512
#define NTOK 32768
#define NE   8
#define BM   64
#define BN   64
#define BK   32
#define NT   (DD / BK)   // 16 k-steps
#define RBLK 1024

typedef unsigned int  u32;
typedef unsigned short u16;
typedef unsigned long long u64;
using bf16x8 = __attribute__((ext_vector_type(8))) short;
using f32x4  = __attribute__((ext_vector_type(4))) float;

// LDS (u16 units): per buffer {Ah, Al, Bh, Bl}, each 64x32 u16 (4KB) -> 16KB/buf, dbuf 32KB
#define OAH 0
#define OAL 2048
#define OBH 4096
#define OBL 6144
#define BUFSZ 8192

__device__ __forceinline__ u32 rne_bf16(float f) {
    u32 u = __float_as_uint(f);
    return (u + 0x7FFFu + ((u >> 16) & 1u)) >> 16;
}
__device__ __forceinline__ void split1(float f, u16& h, u16& l) {
    u32 hb = rne_bf16(f);
    float hf = __uint_as_float(hb << 16);
    float r = f - hf;
    u32 lb = rne_bf16(r);
    h = (u16)hb; l = (u16)lb;
}
__device__ __forceinline__ void split8(const float4& a, const float4& b,
                                       uint4& H, uint4& L) {
    float fs[8] = {a.x, a.y, a.z, a.w, b.x, b.y, b.z, b.w};
    u16 hs[8], ls[8];
#pragma unroll
    for (int i = 0; i < 8; i++) split1(fs[i], hs[i], ls[i]);
    H.x = hs[0] | ((u32)hs[1] << 16); H.y = hs[2] | ((u32)hs[3] << 16);
    H.z = hs[4] | ((u32)hs[5] << 16); H.w = hs[6] | ((u32)hs[7] << 16);
    L.x = ls[0] | ((u32)ls[1] << 16); L.y = ls[2] | ((u32)ls[3] << 16);
    L.z = ls[4] | ((u32)ls[5] << 16); L.w = ls[6] | ((u32)ls[7] << 16);
}

__device__ __forceinline__ void gl16(const void* src, const u16* ldsdst) {
    __builtin_amdgcn_global_load_lds(
        (const __attribute__((address_space(1))) u32*)src,
        (__attribute__((address_space(3))) u32*)(void*)ldsdst, 16, 0, 0);
}

// ---------------- routing: block-aggregated counts ----------------
__global__ __launch_bounds__(RBLK) void route_kernel(
    const float* __restrict__ x,
    const float* __restrict__ Wg,
    const float* __restrict__ bg,
    int t0, int T,
    int* __restrict__ counts,
    int* __restrict__ eids,
    float* __restrict__ wts) {
    __shared__ int lcnt[NE];
    int tid = threadIdx.x;
    if (tid < NE) lcnt[tid] = 0;
    __syncthreads();

    int i = blockIdx.x * RBLK + tid;
    bool active = (i < T);
    int e0 = 0, e1 = 0;
    if (active) {
        int n = t0 + i;
        const float* xr = x + (size_t)n * DD + (DD - 3);
        float x0 = xr[0], x1 = xr[1], x2 = xr[2];
        float g[NE];
#pragma unroll
        for (int e = 0; e < NE; e++)
            g[e] = x0 * Wg[e] + x1 * Wg[NE + e] + x2 * Wg[2 * NE + e] + bg[e];
        float v0 = g[0];
#pragma unroll
        for (int e = 1; e < NE; e++) if (g[e] > v0) { v0 = g[e]; e0 = e; }
        float v1 = -3.0e38f; e1 = -1;
#pragma unroll
        for (int e = 0; e < NE; e++) if (e != e0 && g[e] > v1) { v1 = g[e]; e1 = e; }
        float t = expf(v1 - v0);
        float s = 1.0f / (1.0f + t);
        eids[2 * i] = e0; eids[2 * i + 1] = e1;
        wts[2 * i] = s;  wts[2 * i + 1] = t * s;
    }

    int lane = tid & 63;
#pragma unroll
    for (int k = 0; k < 2; k++) {
        int e = active ? (k ? e1 : e0) : -1;
#pragma unroll
        for (int ex = 0; ex < NE; ex++) {
            u64 m = __ballot(e == ex);
            if (m && lane == 0) atomicAdd(&lcnt[ex], __popcll(m));
        }
    }
    __syncthreads();
    if (tid < NE && lcnt[tid]) atomicAdd(&counts[tid], lcnt[tid]);
}

// ---------------- padded prefix sum (pad to BM=64) ----------------
__global__ void offsets_kernel(const int* __restrict__ counts,
                               int* __restrict__ off,
                               int* __restrict__ cursor) {
    if (threadIdx.x == 0) {
        int acc = 0;
        for (int e = 0; e < NE; e++) {
            off[e] = acc;
            cursor[e] = acc;
            acc += (counts[e] + (BM - 1)) & ~(BM - 1);
        }
        off[NE] = acc;
    }
}

// ---------------- scatter: block/wave-aggregated ----------------
__global__ __launch_bounds__(RBLK) void scatter_kernel(
    int t0, int T,
    const int* __restrict__ eids,
    int* __restrict__ cursor,
    int* __restrict__ list_token,
    int* __restrict__ posl) {
    __shared__ int lcnt[NE], lbase[NE];
    __shared__ int woff[RBLK / 64][NE];
    int tid = threadIdx.x, lane = tid & 63, wv = tid >> 6;
    int i = blockIdx.x * RBLK + tid;
    bool active = (i < T);
    u64 lmask = (1ull << lane) - 1ull;

#pragma unroll
    for (int k = 0; k < 2; k++) {
        if (tid < NE) lcnt[tid] = 0;
        __syncthreads();
        int e = active ? eids[2 * i + k] : -1;
        u64 mymask = 0;
#pragma unroll
        for (int ex = 0; ex < NE; ex++) {
            u64 m = __ballot(e == ex);
            if (e == ex) mymask = m;
            if (m && lane == 0) woff[wv][ex] = atomicAdd(&lcnt[ex], __popcll(m));
        }
        __syncthreads();
        if (tid < NE) lbase[tid] = lcnt[tid] ? atomicAdd(&cursor[tid], lcnt[tid]) : 0;
        __syncthreads();
        if (active) {
            int p = lbase[e] + woff[wv][e] + __popcll(mymask & lmask);
            list_token[p] = t0 + i;
            posl[2 * i + k] = p;
        }
        __syncthreads();
    }
}

// ---------------- weight transpose + hi/lo split ----------------
__global__ void convert_w(const float* __restrict__ Wh,
                          const float* __restrict__ Wo,
                          u16* __restrict__ WtHi, u16* __restrict__ WtLo) {
    __shared__ float tile[32][33];
    int z = blockIdx.z;             // e*4 + l
    int e = z >> 2, l = z & 3;
    const float* src = (l < 3) ? (Wh + ((size_t)e * 3 + l) * DD * DD)
                               : (Wo + (size_t)e * DD * DD);
    int bx = blockIdx.x, by = blockIdx.y;
    int tx = threadIdx.x, ty = threadIdx.y; // 32 x 8
#pragma unroll
    for (int j = 0; j < 4; j++)
        tile[ty + j * 8][tx] = src[(size_t)(by * 32 + ty + j * 8) * DD + bx * 32 + tx];
    __syncthreads();
    u16* dh = WtHi + (size_t)z * DD * DD;
    u16* dl = WtLo + (size_t)z * DD * DD;
#pragma unroll
    for (int j = 0; j < 4; j++) {
        int n = bx * 32 + ty + j * 8;
        int k = by * 32 + tx;
        u16 h, lo;
        split1(tile[tx][ty + j * 8], h, lo);
        dh[(size_t)n * DD + k] = h;
        dl[(size_t)n * DD + k] = lo;
    }
}

// ---------------- split-bf16 MFMA GEMM, 64x64x32, 4 waves, dbuf + counted vmcnt ----------------
template <bool GATHER, bool RELU, bool OUTF32>
__global__ __launch_bounds__(256, 4) void moe_gemm(
    const float* __restrict__ Xf,
    const u16* __restrict__ Ahi, const u16* __restrict__ Alo,
    const int* __restrict__ list_token,
    const u16* __restrict__ WtHi, const u16* __restrict__ WtLo,
    int layer,
    const float* __restrict__ bptr, int bestride,
    const int* __restrict__ off,
    u16* __restrict__ Chi, u16* __restrict__ Clo,
    float* __restrict__ Cf)
{
    // XCD-bijective swizzle (grid multiple of 8), cb-minor within XCD chunk:
    // consecutive tiles on one XCD share the same A row-panel (L2 reuse).
    u32 nb = gridDim.x, qq = nb >> 3, bid = blockIdx.x;
    u32 wg = (bid & 7) * qq + (bid >> 3);
    int rb = (int)(wg >> 3) * BM;
    if (rb >= off[NE]) return;
    int cb = (int)(wg & 7) * BN;
    int e = 0;
#pragma unroll
    for (int s = 1; s < NE; s++) if (rb >= off[s]) e = s;

    __shared__ u16 lds[2 * BUFSZ];   // 32 KiB

    const int tid = threadIdx.x;
    const int lane = tid & 63, wv = tid >> 6;

    // staging: chunk c = tid; row = c>>2 in [0,64), su = c&3 (16B unit of 4)
    const int srow = tid >> 2, su = tid & 3;
    const int us = su ^ ((srow >> 1) & 3);   // pre-swizzled source unit

    const size_t wbase = ((size_t)e * 4 + layer) * (size_t)DD * DD;
    const u16* bSH = WtHi + wbase + (size_t)(cb + srow) * DD + us * 8;
    const u16* bSL = WtLo + wbase + (size_t)(cb + srow) * DD + us * 8;

    const u16 *aSH = nullptr, *aSL = nullptr;
    const float* aF = nullptr;
    int tokr = 0;
    if (GATHER) {
        tokr = list_token[rb + srow];
        aF = Xf + (size_t)(tokr < 0 ? 0 : tokr) * DD + us * 8;
    } else {
        aSH = Ahi + (size_t)(rb + srow) * DD + us * 8;
        aSL = Alo + (size_t)(rb + srow) * DD + us * 8;
    }

    // MFMA read mapping: 4 waves 2x2, wave-tile 32x32
    const int r15 = lane & 15, lg = lane >> 4;
    const int wr = (wv >> 1) * 32, wc = (wv & 1) * 32;
    u32 aoff[2], boff[2];
#pragma unroll
    for (int i = 0; i < 2; i++) {
        int ar = wr + i * 16 + r15;
        aoff[i] = (u32)(ar * 32 + (lg ^ ((ar >> 1) & 3)) * 8);
        int br = wc + i * 16 + r15;
        boff[i] = (u32)(br * 32 + (lg ^ ((br >> 1) & 3)) * 8);
    }

    const int wvb = wv * 512;   // wave chunk base (u16): 64 chunks * 8 u16

    f32x4 acc[2][2];
#pragma unroll
    for (int i = 0; i < 2; i++)
#pragma unroll
        for (int j = 0; j < 2; j++) acc[i][j] = (f32x4){0.f, 0.f, 0.f, 0.f};

#define STG_B(bb_, k_)                                       \
    { gl16(bSH + (k_), &lds[(bb_) + OBH + wvb]);             \
      gl16(bSL + (k_), &lds[(bb_) + OBL + wvb]); }
#define STG_A(bb_, k_)                                       \
    { gl16(aSH + (k_), &lds[(bb_) + OAH + wvb]);             \
      gl16(aSL + (k_), &lds[(bb_) + OAL + wvb]); }

    // prologue: stage tile 0 into buf 0
    STG_B(0, 0);
    if (!GATHER) STG_A(0, 0);

    int bb = 0;
    for (int t = 0; t < NT; t++) {
        if (GATHER) {
            const float4* fp = (const float4*)(aF + t * BK);
            float4 f0 = fp[0], f1 = fp[1];
            if (tokr < 0) { f0 = make_float4(0.f, 0.f, 0.f, 0.f); f1 = f0; }
            if (t + 1 < NT) {
                STG_B(bb ^ BUFSZ, (t + 1) * BK);
                asm volatile("s_waitcnt vmcnt(2)" ::: "memory");
            } else {
                asm volatile("s_waitcnt vmcnt(0)" ::: "memory");
            }
            uint4 H, L;
            split8(f0, f1, H, L);
            *(uint4*)&lds[bb + OAH + srow * 32 + su * 8] = H;
            *(uint4*)&lds[bb + OAL + srow * 32 + su * 8] = L;
            asm volatile("s_waitcnt lgkmcnt(0)" ::: "memory");
            __builtin_amdgcn_s_barrier();
        } else {
            if (t + 1 < NT) {
                STG_A(bb ^ BUFSZ, (t + 1) * BK);
                STG_B(bb ^ BUFSZ, (t + 1) * BK);
                asm volatile("s_waitcnt vmcnt(4)" ::: "memory");
            } else {
                asm volatile("s_waitcnt vmcnt(0)" ::: "memory");
            }
            __builtin_amdgcn_s_barrier();
        }

        // ---- compute on buf bb: 8 ds_read_b128 + 12 MFMA ----
        bf16x8 ah[2], al[2], bh2[2], bl2[2];
#pragma unroll
        for (int i = 0; i < 2; i++) {
            ah[i]  = *(const bf16x8*)&lds[bb + OAH + aoff[i]];
            al[i]  = *(const bf16x8*)&lds[bb + OAL + aoff[i]];
            bh2[i] = *(const bf16x8*)&lds[bb + OBH + boff[i]];
            bl2[i] = *(const bf16x8*)&lds[bb + OBL + boff[i]];
        }
#pragma unroll
        for (int mi = 0; mi < 2; mi++)
#pragma unroll
            for (int ni = 0; ni < 2; ni++) {
                acc[mi][ni] = __builtin_amdgcn_mfma_f32_16x16x32_bf16(ah[mi], bh2[ni], acc[mi][ni], 0, 0, 0);
                acc[mi][ni] = __builtin_amdgcn_mfma_f32_16x16x32_bf16(al[mi], bh2[ni], acc[mi][ni], 0, 0, 0);
                acc[mi][ni] = __builtin_amdgcn_mfma_f32_16x16x32_bf16(ah[mi], bl2[ni], acc[mi][ni], 0, 0, 0);
            }
        asm volatile("" ::: "memory");
        __builtin_amdgcn_s_barrier();
        bb ^= BUFSZ;
    }
#undef STG_A
#undef STG_B

    // ---- epilogue: bias (+relu); write fp32 or hi/lo bf16 ----
#pragma unroll
    for (int ni = 0; ni < 2; ni++) {
        int col = cb + wc + ni * 16 + r15;
        float bbias = bptr[e * bestride + col];
#pragma unroll
        for (int mi = 0; mi < 2; mi++) {
            int row0 = rb + wr + mi * 16 + lg * 4;
#pragma unroll
            for (int rr = 0; rr < 4; rr++) {
                float v = acc[mi][ni][rr] + bbias;
                if (RELU) v = fmaxf(v, 0.f);
                size_t idx = (size_t)(row0 + rr) * DD + col;
                if (OUTF32) {
                    Cf[idx] = v;
                } else {
                    u16 h, lo;
                    split1(v, h, lo);
                    Chi[idx] = h;
                    Clo[idx] = lo;
                }
            }
        }
    }
}

// ---------------- combine ----------------
__global__ void combine_kernel(int t0, int T,
                               const float* __restrict__ y,
                               const int* __restrict__ posl,
                               const float* __restrict__ wts,
                               float* __restrict__ out) {
    int idx = blockIdx.x * blockDim.x + threadIdx.x;
    if (idx >= T * (DD / 4)) return;
    int i = idx >> 7;
    int j = idx & 127;
    int p0 = posl[2 * i], p1 = posl[2 * i + 1];
    float w0 = wts[2 * i], w1 = wts[2 * i + 1];
    float4 a = ((const float4*)(y + (size_t)p0 * DD))[j];
    float4 b = ((const float4*)(y + (size_t)p1 * DD))[j];
    float4 c;
    c.x = w0 * a.x + w1 * b.x;
    c.y = w0 * a.y + w1 * b.y;
    c.z = w0 * a.z + w1 * b.z;
    c.w = w0 * a.w + w1 * b.w;
    ((float4*)(out + (size_t)(t0 + i) * DD))[j] = c;
}

extern "C" void kernel_launch(void* const* d_in, const int* in_sizes, int n_in,
                              void* d_out, int out_size, void* d_ws, size_t ws_size,
                              hipStream_t stream) {
    const float* x  = (const float*)d_in[0];
    const float* Wg = (const float*)d_in[1];
    const float* bg = (const float*)d_in[2];
    const float* Wh = (const float*)d_in[3];
    const float* bh = (const float*)d_in[4];
    const float* Wo = (const float*)d_in[5];
    const float* bo = (const float*)d_in[6];
    float* out = (float*)d_out;

    const size_t WT_ELEMS = (size_t)NE * 4 * DD * DD;
    int T = NTOK;
    while (T > 64) {
        size_t C = 2 * (size_t)T + NE * BM;
        size_t need = 4096 + 2 * WT_ELEMS * 2 + 3 * ((size_t)T * 2 * 4)
                    + C * 4 + 512 + 4 * (C * (size_t)DD * 2);
        if (need <= ws_size) break;
        T >>= 1;
    }
    int phases = (NTOK + T - 1) / T;
    size_t C = 2 * (size_t)T + NE * BM;

    char* p = (char*)d_ws;
    int* counts = (int*)p;
    int* off    = (int*)(p + 64);
    int* cursor = (int*)(p + 128);
    char* q = p + 4096;
    u16* WtHi = (u16*)q;  q += WT_ELEMS * 2;
    u16* WtLo = (u16*)q;  q += WT_ELEMS * 2;
    int* eids = (int*)q;  q += (size_t)T * 2 * 4;
    int* posl = (int*)q;  q += (size_t)T * 2 * 4;
    float* wts = (float*)q; q += (size_t)T * 2 * 4;
    int* list_token = (int*)q; q += C * 4;
    q = (char*)(((uintptr_t)q + 255) & ~(uintptr_t)255);
    u16* bufA_hi = (u16*)q; q += C * DD * 2;
    u16* bufA_lo = (u16*)q; q += C * DD * 2;
    u16* bufB_hi = (u16*)q; q += C * DD * 2;   // final fp32 y aliases hi+lo
    u16* bufB_lo = (u16*)q; q += C * DD * 2;
    float* yf = (float*)bufB_hi;

    convert_w<<<dim3(16, 16, 32), dim3(32, 8), 0, stream>>>(Wh, Wo, WtHi, WtLo);

    for (int ph = 0; ph < phases; ph++) {
        int t0 = ph * T;
        int Tc = (NTOK - t0 < T) ? (NTOK - t0) : T;

        hipMemsetAsync(counts, 0, 256, stream);
        hipMemsetAsync(list_token, 0xFF, C * 4, stream);

        route_kernel<<<(Tc + RBLK - 1) / RBLK, RBLK, 0, stream>>>(
            x, Wg, bg, t0, Tc, counts, eids, wts);
        offsets_kernel<<<1, 64, 0, stream>>>(counts, off, cursor);
        scatter_kernel<<<(Tc + RBLK - 1) / RBLK, RBLK, 0, stream>>>(
            t0, Tc, eids, cursor, list_token, posl);

        // grid: (C/BM) row-panels x 8 col-blocks, 1-D, multiple of 8 for XCD swizzle
        unsigned NB = (unsigned)(C / BM) * (DD / BN);
        moe_gemm<true, true, false><<<NB, 256, 0, stream>>>(
            x, nullptr, nullptr, list_token, WtHi, WtLo, 0,
            bh, 3 * DD, off, bufA_hi, bufA_lo, nullptr);
        moe_gemm<false, true, false><<<NB, 256, 0, stream>>>(
            nullptr, bufA_hi, bufA_lo, nullptr, WtHi, WtLo, 1,
            bh + DD, 3 * DD, off, bufB_hi, bufB_lo, nullptr);
        moe_gemm<false, true, false><<<NB, 256, 0, stream>>>(
            nullptr, bufB_hi, bufB_lo, nullptr, WtHi, WtLo, 2,
            bh + 2 * DD, 3 * DD, off, bufA_hi, bufA_lo, nullptr);
        moe_gemm<false, false, true><<<NB, 256, 0, stream>>>(
            nullptr, bufA_hi, bufA_lo, nullptr, WtHi, WtLo, 3,
            bo, DD, off, nullptr, nullptr, yf);

        combine_kernel<<<((size_t)Tc * (DD / 4) + 255) / 256, 256, 0, stream>>>(
            t0, Tc, yf, posl, wts, out);
    }
}

// Round 6
// 614.138 us; speedup vs baseline: 1.4171x; 1.2139x over previous
//
#include <hip/hip_runtime.h>
#include <cstdint>
#include <cstddef>

#define DD   512
#define NTOK 32768
#define NE   8
#define BM   128
#define BN   128
#define BK   32
#define NT   (DD / BK)   // 16 k-steps
#define RBLK 1024

typedef unsigned int  u32;
typedef unsigned short u16;
typedef unsigned long long u64;
using bf16x8 = __attribute__((ext_vector_type(8))) short;
using f32x4  = __attribute__((ext_vector_type(4))) float;

// LDS (u16 units): single buffer {Ah, Al, Bh, Bl}, each 128x32 u16 (8KB) -> 32KB
#define OAH 0
#define OAL 4096
#define OBH 8192
#define OBL 12288

__device__ __forceinline__ u32 rne_bf16(float f) {
    u32 u = __float_as_uint(f);
    return (u + 0x7FFFu + ((u >> 16) & 1u)) >> 16;
}
__device__ __forceinline__ void split1(float f, u16& h, u16& l) {
    u32 hb = rne_bf16(f);
    float hf = __uint_as_float(hb << 16);
    float r = f - hf;
    u32 lb = rne_bf16(r);
    h = (u16)hb; l = (u16)lb;
}
__device__ __forceinline__ void split8(const float4& a, const float4& b,
                                       uint4& H, uint4& L) {
    float fs[8] = {a.x, a.y, a.z, a.w, b.x, b.y, b.z, b.w};
    u16 hs[8], ls[8];
#pragma unroll
    for (int i = 0; i < 8; i++) split1(fs[i], hs[i], ls[i]);
    H.x = hs[0] | ((u32)hs[1] << 16); H.y = hs[2] | ((u32)hs[3] << 16);
    H.z = hs[4] | ((u32)hs[5] << 16); H.w = hs[6] | ((u32)hs[7] << 16);
    L.x = ls[0] | ((u32)ls[1] << 16); L.y = ls[2] | ((u32)ls[3] << 16);
    L.z = ls[4] | ((u32)ls[5] << 16); L.w = ls[6] | ((u32)ls[7] << 16);
}

__device__ __forceinline__ void gl16(const void* src, const u16* ldsdst) {
    __builtin_amdgcn_global_load_lds(
        (const __attribute__((address_space(1))) u32*)src,
        (__attribute__((address_space(3))) u32*)(void*)ldsdst, 16, 0, 0);
}

// ---------------- routing: block-aggregated counts ----------------
__global__ __launch_bounds__(RBLK) void route_kernel(
    const float* __restrict__ x,
    const float* __restrict__ Wg,
    const float* __restrict__ bg,
    int t0, int T,
    int* __restrict__ counts,
    int* __restrict__ eids,
    float* __restrict__ wts) {
    __shared__ int lcnt[NE];
    int tid = threadIdx.x;
    if (tid < NE) lcnt[tid] = 0;
    __syncthreads();

    int i = blockIdx.x * RBLK + tid;
    bool active = (i < T);
    int e0 = 0, e1 = 0;
    if (active) {
        int n = t0 + i;
        const float* xr = x + (size_t)n * DD + (DD - 3);
        float x0 = xr[0], x1 = xr[1], x2 = xr[2];
        float g[NE];
#pragma unroll
        for (int e = 0; e < NE; e++)
            g[e] = x0 * Wg[e] + x1 * Wg[NE + e] + x2 * Wg[2 * NE + e] + bg[e];
        float v0 = g[0];
#pragma unroll
        for (int e = 1; e < NE; e++) if (g[e] > v0) { v0 = g[e]; e0 = e; }
        float v1 = -3.0e38f; e1 = -1;
#pragma unroll
        for (int e = 0; e < NE; e++) if (e != e0 && g[e] > v1) { v1 = g[e]; e1 = e; }
        float t = expf(v1 - v0);
        float s = 1.0f / (1.0f + t);
        eids[2 * i] = e0; eids[2 * i + 1] = e1;
        wts[2 * i] = s;  wts[2 * i + 1] = t * s;
    }

    int lane = tid & 63;
#pragma unroll
    for (int k = 0; k < 2; k++) {
        int e = active ? (k ? e1 : e0) : -1;
#pragma unroll
        for (int ex = 0; ex < NE; ex++) {
            u64 m = __ballot(e == ex);
            if (m && lane == 0) atomicAdd(&lcnt[ex], __popcll(m));
        }
    }
    __syncthreads();
    if (tid < NE && lcnt[tid]) atomicAdd(&counts[tid], lcnt[tid]);
}

// ---------------- padded prefix sum (pad to BM) ----------------
__global__ void offsets_kernel(const int* __restrict__ counts,
                               int* __restrict__ off,
                               int* __restrict__ cursor) {
    if (threadIdx.x == 0) {
        int acc = 0;
        for (int e = 0; e < NE; e++) {
            off[e] = acc;
            cursor[e] = acc;
            acc += (counts[e] + (BM - 1)) & ~(BM - 1);
        }
        off[NE] = acc;
    }
}

// ---------------- scatter: block/wave-aggregated ----------------
__global__ __launch_bounds__(RBLK) void scatter_kernel(
    int t0, int T,
    const int* __restrict__ eids,
    int* __restrict__ cursor,
    int* __restrict__ list_token,
    int* __restrict__ posl) {
    __shared__ int lcnt[NE], lbase[NE];
    __shared__ int woff[RBLK / 64][NE];
    int tid = threadIdx.x, lane = tid & 63, wv = tid >> 6;
    int i = blockIdx.x * RBLK + tid;
    bool active = (i < T);
    u64 lmask = (1ull << lane) - 1ull;

#pragma unroll
    for (int k = 0; k < 2; k++) {
        if (tid < NE) lcnt[tid] = 0;
        __syncthreads();
        int e = active ? eids[2 * i + k] : -1;
        u64 mymask = 0;
#pragma unroll
        for (int ex = 0; ex < NE; ex++) {
            u64 m = __ballot(e == ex);
            if (e == ex) mymask = m;
            if (m && lane == 0) woff[wv][ex] = atomicAdd(&lcnt[ex], __popcll(m));
        }
        __syncthreads();
        if (tid < NE) lbase[tid] = lcnt[tid] ? atomicAdd(&cursor[tid], lcnt[tid]) : 0;
        __syncthreads();
        if (active) {
            int p = lbase[e] + woff[wv][e] + __popcll(mymask & lmask);
            list_token[p] = t0 + i;
            posl[2 * i + k] = p;
        }
        __syncthreads();
    }
}

// ---------------- weight transpose + hi/lo split ----------------
__global__ void convert_w(const float* __restrict__ Wh,
                          const float* __restrict__ Wo,
                          u16* __restrict__ WtHi, u16* __restrict__ WtLo) {
    __shared__ float tile[32][33];
    int z = blockIdx.z;             // e*4 + l
    int e = z >> 2, l = z & 3;
    const float* src = (l < 3) ? (Wh + ((size_t)e * 3 + l) * DD * DD)
                               : (Wo + (size_t)e * DD * DD);
    int bx = blockIdx.x, by = blockIdx.y;
    int tx = threadIdx.x, ty = threadIdx.y; // 32 x 8
#pragma unroll
    for (int j = 0; j < 4; j++)
        tile[ty + j * 8][tx] = src[(size_t)(by * 32 + ty + j * 8) * DD + bx * 32 + tx];
    __syncthreads();
    u16* dh = WtHi + (size_t)z * DD * DD;
    u16* dl = WtLo + (size_t)z * DD * DD;
#pragma unroll
    for (int j = 0; j < 4; j++) {
        int n = bx * 32 + ty + j * 8;
        int k = by * 32 + tx;
        u16 h, lo;
        split1(tile[tx][ty + j * 8], h, lo);
        dh[(size_t)n * DD + k] = h;
        dl[(size_t)n * DD + k] = lo;
    }
}

// ---------------- split-bf16 MFMA GEMM: 128x128x32, 4 waves, wave-tile 64x64 ----------------
template <bool GATHER, bool RELU, bool OUTF32>
__global__ __launch_bounds__(256, 3) void moe_gemm(
    const float* __restrict__ Xf,
    const u16* __restrict__ Ahi, const u16* __restrict__ Alo,
    const int* __restrict__ list_token,
    const u16* __restrict__ WtHi, const u16* __restrict__ WtLo,
    int layer,
    const float* __restrict__ bptr, int bestride,
    const int* __restrict__ off,
    u16* __restrict__ Chi, u16* __restrict__ Clo,
    float* __restrict__ Cf)
{
    // XCD-bijective swizzle (grid multiple of 8); cb-minor within XCD chunk
    u32 nb = gridDim.x, qq = nb >> 3, bid = blockIdx.x;
    u32 wg = (bid & 7) * qq + (bid >> 3);
    int rb = (int)(wg >> 2) * BM;
    if (rb >= off[NE]) return;
    int cb = (int)(wg & 3) * BN;
    int e = 0;
#pragma unroll
    for (int s = 1; s < NE; s++) if (rb >= off[s]) e = s;

    __shared__ u16 lds[16384];   // 32 KiB

    const int tid = threadIdx.x;
    const int lane = tid & 63, wv = tid >> 6;

    // staging: per array, thread covers chunks cc = j*256 + tid (j=0,1)
    // row = cc>>2, linear unit u = tid&3, swizzled logical unit us = u ^ ((row>>1)&3)
    int rowj[2], usj[2];
#pragma unroll
    for (int j = 0; j < 2; j++) {
        rowj[j] = j * 64 + (tid >> 2);
        usj[j]  = (tid & 3) ^ ((rowj[j] >> 1) & 3);
    }

    const size_t wbase = ((size_t)e * 4 + layer) * (size_t)DD * DD;
    const u16 *bSH[2], *bSL[2];
    const u16 *aSH[2], *aSL[2];
    const float* aF[2];
    int tokj[2] = {0, 0};
#pragma unroll
    for (int j = 0; j < 2; j++) {
        bSH[j] = WtHi + wbase + (size_t)(cb + rowj[j]) * DD + usj[j] * 8;
        bSL[j] = WtLo + wbase + (size_t)(cb + rowj[j]) * DD + usj[j] * 8;
        if (GATHER) {
            tokj[j] = list_token[rb + rowj[j]];
            aF[j] = Xf + (size_t)(tokj[j] < 0 ? 0 : tokj[j]) * DD + usj[j] * 8;
        } else {
            aSH[j] = Ahi + (size_t)(rb + rowj[j]) * DD + usj[j] * 8;
            aSL[j] = Alo + (size_t)(rb + rowj[j]) * DD + usj[j] * 8;
        }
    }
    // wave-uniform LDS chunk bases (u16 idx): chunk (j*256 + wv*64), lane auto-offset x16B
    const int cb8[2] = { wv * 512, 2048 + wv * 512 };

    // MFMA read mapping: 2x2 wave grid, wave-tile 64x64
    const int r15 = lane & 15, lg = lane >> 4;
    const int wr = (wv >> 1) * 64, wc = (wv & 1) * 64;
    u32 aoff[4], boff[4];
#pragma unroll
    for (int i = 0; i < 4; i++) {
        int ar = wr + i * 16 + r15;
        aoff[i] = (u32)(ar * 32 + (lg ^ ((ar >> 1) & 3)) * 8);
        int br = wc + i * 16 + r15;
        boff[i] = (u32)(br * 32 + (lg ^ ((br >> 1) & 3)) * 8);
    }

    f32x4 acc[4][4];
#pragma unroll
    for (int i = 0; i < 4; i++)
#pragma unroll
        for (int j = 0; j < 4; j++) acc[i][j] = (f32x4){0.f, 0.f, 0.f, 0.f};

    for (int t = 0; t < NT; t++) {
        const int k0 = t * BK;
        // ---- stage tile t ----
#pragma unroll
        for (int j = 0; j < 2; j++) {
            gl16(bSH[j] + k0, &lds[OBH + cb8[j]]);
            gl16(bSL[j] + k0, &lds[OBL + cb8[j]]);
        }
        if (GATHER) {
#pragma unroll
            for (int j = 0; j < 2; j++) {
                const float4* fp = (const float4*)(aF[j] + k0);
                float4 f0 = fp[0], f1 = fp[1];
                if (tokj[j] < 0) { f0 = make_float4(0.f, 0.f, 0.f, 0.f); f1 = f0; }
                uint4 H, L;
                split8(f0, f1, H, L);
                *(uint4*)&lds[OAH + rowj[j] * 32 + (tid & 3) * 8] = H;
                *(uint4*)&lds[OAL + rowj[j] * 32 + (tid & 3) * 8] = L;
            }
        } else {
#pragma unroll
            for (int j = 0; j < 2; j++) {
                gl16(aSH[j] + k0, &lds[OAH + cb8[j]]);
                gl16(aSL[j] + k0, &lds[OAL + cb8[j]]);
            }
        }
        __syncthreads();

        // ---- compute: 16 ds_read_b128 + 48 MFMA ----
        bf16x8 ah[4], al[4];
#pragma unroll
        for (int mi = 0; mi < 4; mi++) {
            ah[mi] = *(const bf16x8*)&lds[OAH + aoff[mi]];
            al[mi] = *(const bf16x8*)&lds[OAL + aoff[mi]];
        }
#pragma unroll
        for (int ni = 0; ni < 4; ni++) {
            bf16x8 bh2 = *(const bf16x8*)&lds[OBH + boff[ni]];
            bf16x8 bl2 = *(const bf16x8*)&lds[OBL + boff[ni]];
#pragma unroll
            for (int mi = 0; mi < 4; mi++) {
                acc[mi][ni] = __builtin_amdgcn_mfma_f32_16x16x32_bf16(ah[mi], bh2, acc[mi][ni], 0, 0, 0);
                acc[mi][ni] = __builtin_amdgcn_mfma_f32_16x16x32_bf16(al[mi], bh2, acc[mi][ni], 0, 0, 0);
                acc[mi][ni] = __builtin_amdgcn_mfma_f32_16x16x32_bf16(ah[mi], bl2, acc[mi][ni], 0, 0, 0);
            }
        }
        __syncthreads();
    }

    // ---- epilogue: bias (+relu); write fp32 or hi/lo bf16 ----
#pragma unroll
    for (int ni = 0; ni < 4; ni++) {
        int col = cb + wc + ni * 16 + r15;
        float bbias = bptr[e * bestride + col];
#pragma unroll
        for (int mi = 0; mi < 4; mi++) {
            int row0 = rb + wr + mi * 16 + lg * 4;
#pragma unroll
            for (int rr = 0; rr < 4; rr++) {
                float v = acc[mi][ni][rr] + bbias;
                if (RELU) v = fmaxf(v, 0.f);
                size_t idx = (size_t)(row0 + rr) * DD + col;
                if (OUTF32) {
                    Cf[idx] = v;
                } else {
                    u16 h, lo;
                    split1(v, h, lo);
                    Chi[idx] = h;
                    Clo[idx] = lo;
                }
            }
        }
    }
}

// ---------------- combine ----------------
__global__ void combine_kernel(int t0, int T,
                               const float* __restrict__ y,
                               const int* __restrict__ posl,
                               const float* __restrict__ wts,
                               float* __restrict__ out) {
    int idx = blockIdx.x * blockDim.x + threadIdx.x;
    if (idx >= T * (DD / 4)) return;
    int i = idx >> 7;
    int j = idx & 127;
    int p0 = posl[2 * i], p1 = posl[2 * i + 1];
    float w0 = wts[2 * i], w1 = wts[2 * i + 1];
    float4 a = ((const float4*)(y + (size_t)p0 * DD))[j];
    float4 b = ((const float4*)(y + (size_t)p1 * DD))[j];
    float4 c;
    c.x = w0 * a.x + w1 * b.x;
    c.y = w0 * a.y + w1 * b.y;
    c.z = w0 * a.z + w1 * b.z;
    c.w = w0 * a.w + w1 * b.w;
    ((float4*)(out + (size_t)(t0 + i) * DD))[j] = c;
}

extern "C" void kernel_launch(void* const* d_in, const int* in_sizes, int n_in,
                              void* d_out, int out_size, void* d_ws, size_t ws_size,
                              hipStream_t stream) {
    const float* x  = (const float*)d_in[0];
    const float* Wg = (const float*)d_in[1];
    const float* bg = (const float*)d_in[2];
    const float* Wh = (const float*)d_in[3];
    const float* bh = (const float*)d_in[4];
    const float* Wo = (const float*)d_in[5];
    const float* bo = (const float*)d_in[6];
    float* out = (float*)d_out;

    const size_t WT_ELEMS = (size_t)NE * 4 * DD * DD;
    int T = NTOK;
    while (T > 64) {
        size_t C = 2 * (size_t)T + NE * BM;
        size_t need = 4096 + 2 * WT_ELEMS * 2 + 3 * ((size_t)T * 2 * 4)
                    + C * 4 + 512 + 4 * (C * (size_t)DD * 2);
        if (need <= ws_size) break;
        T >>= 1;
    }
    int phases = (NTOK + T - 1) / T;
    size_t C = 2 * (size_t)T + NE * BM;

    char* p = (char*)d_ws;
    int* counts = (int*)p;
    int* off    = (int*)(p + 64);
    int* cursor = (int*)(p + 128);
    char* q = p + 4096;
    u16* WtHi = (u16*)q;  q += WT_ELEMS * 2;
    u16* WtLo = (u16*)q;  q += WT_ELEMS * 2;
    int* eids = (int*)q;  q += (size_t)T * 2 * 4;
    int* posl = (int*)q;  q += (size_t)T * 2 * 4;
    float* wts = (float*)q; q += (size_t)T * 2 * 4;
    int* list_token = (int*)q; q += C * 4;
    q = (char*)(((uintptr_t)q + 255) & ~(uintptr_t)255);
    u16* bufA_hi = (u16*)q; q += C * DD * 2;
    u16* bufA_lo = (u16*)q; q += C * DD * 2;
    u16* bufB_hi = (u16*)q; q += C * DD * 2;   // final fp32 y aliases hi+lo
    u16* bufB_lo = (u16*)q; q += C * DD * 2;
    float* yf = (float*)bufB_hi;

    convert_w<<<dim3(16, 16, 32), dim3(32, 8), 0, stream>>>(Wh, Wo, WtHi, WtLo);

    for (int ph = 0; ph < phases; ph++) {
        int t0 = ph * T;
        int Tc = (NTOK - t0 < T) ? (NTOK - t0) : T;

        hipMemsetAsync(counts, 0, 256, stream);
        hipMemsetAsync(list_token, 0xFF, C * 4, stream);

        route_kernel<<<(Tc + RBLK - 1) / RBLK, RBLK, 0, stream>>>(
            x, Wg, bg, t0, Tc, counts, eids, wts);
        offsets_kernel<<<1, 64, 0, stream>>>(counts, off, cursor);
        scatter_kernel<<<(Tc + RBLK - 1) / RBLK, RBLK, 0, stream>>>(
            t0, Tc, eids, cursor, list_token, posl);

        // grid: (C/BM) row-panels x 4 col-blocks, 1-D, multiple of 8 for XCD swizzle
        unsigned NB = (unsigned)(C / BM) * (DD / BN);
        moe_gemm<true, true, false><<<NB, 256, 0, stream>>>(
            x, nullptr, nullptr, list_token, WtHi, WtLo, 0,
            bh, 3 * DD, off, bufA_hi, bufA_lo, nullptr);
        moe_gemm<false, true, false><<<NB, 256, 0, stream>>>(
            nullptr, bufA_hi, bufA_lo, nullptr, WtHi, WtLo, 1,
            bh + DD, 3 * DD, off, bufB_hi, bufB_lo, nullptr);
        moe_gemm<false, true, false><<<NB, 256, 0, stream>>>(
            nullptr, bufB_hi, bufB_lo, nullptr, WtHi, WtLo, 2,
            bh + 2 * DD, 3 * DD, off, bufA_hi, bufA_lo, nullptr);
        moe_gemm<false, false, true><<<NB, 256, 0, stream>>>(
            nullptr, bufA_hi, bufA_lo, nullptr, WtHi, WtLo, 3,
            bo, DD, off, nullptr, nullptr, yf);

        combine_kernel<<<((size_t)Tc * (DD / 4) + 255) / 256, 256, 0, stream>>>(
            t0, Tc, yf, posl, wts, out);
    }
}

// Round 7
// 296.315 us; speedup vs baseline: 2.9370x; 2.0726x over previous
//
#include <hip/hip_runtime.h>
#include <cstdint>
#include <cstddef>

#define DD   512
#define NTOK 32768
#define NE   8
#define BM   128
#define BN   128
#define BK   32
#define NT   (DD / BK)   // 16 k-steps
#define RBLK 1024

typedef unsigned int  u32;
typedef unsigned short u16;
typedef unsigned long long u64;
using f16x8 = __attribute__((ext_vector_type(8))) _Float16;
using f32x4 = __attribute__((ext_vector_type(4))) float;

// LDS (u16 units): single buffer {A, B}, each 128x32 f16 (8KB) -> 16KB
#define OA 0
#define OB 4096

__device__ __forceinline__ u16 f16bits(float f) {
    union { _Float16 h; u16 u; } p;
    p.h = (_Float16)f;
    return p.u;
}
__device__ __forceinline__ uint4 pack_f16x8(const float4& a, const float4& b) {
    uint4 r;
    r.x = (u32)f16bits(a.x) | ((u32)f16bits(a.y) << 16);
    r.y = (u32)f16bits(a.z) | ((u32)f16bits(a.w) << 16);
    r.z = (u32)f16bits(b.x) | ((u32)f16bits(b.y) << 16);
    r.w = (u32)f16bits(b.z) | ((u32)f16bits(b.w) << 16);
    return r;
}

__device__ __forceinline__ void gl16(const void* src, const u16* ldsdst) {
    __builtin_amdgcn_global_load_lds(
        (const __attribute__((address_space(1))) u32*)src,
        (__attribute__((address_space(3))) u32*)(void*)ldsdst, 16, 0, 0);
}

// ---------------- routing: block-aggregated counts ----------------
__global__ __launch_bounds__(RBLK) void route_kernel(
    const float* __restrict__ x,
    const float* __restrict__ Wg,
    const float* __restrict__ bg,
    int t0, int T,
    int* __restrict__ counts,
    int* __restrict__ eids,
    float* __restrict__ wts) {
    __shared__ int lcnt[NE];
    int tid = threadIdx.x;
    if (tid < NE) lcnt[tid] = 0;
    __syncthreads();

    int i = blockIdx.x * RBLK + tid;
    bool active = (i < T);
    int e0 = 0, e1 = 0;
    if (active) {
        int n = t0 + i;
        const float* xr = x + (size_t)n * DD + (DD - 3);
        float x0 = xr[0], x1 = xr[1], x2 = xr[2];
        float g[NE];
#pragma unroll
        for (int e = 0; e < NE; e++)
            g[e] = x0 * Wg[e] + x1 * Wg[NE + e] + x2 * Wg[2 * NE + e] + bg[e];
        float v0 = g[0];
#pragma unroll
        for (int e = 1; e < NE; e++) if (g[e] > v0) { v0 = g[e]; e0 = e; }
        float v1 = -3.0e38f; e1 = -1;
#pragma unroll
        for (int e = 0; e < NE; e++) if (e != e0 && g[e] > v1) { v1 = g[e]; e1 = e; }
        float t = expf(v1 - v0);
        float s = 1.0f / (1.0f + t);
        eids[2 * i] = e0; eids[2 * i + 1] = e1;
        wts[2 * i] = s;  wts[2 * i + 1] = t * s;
    }

    int lane = tid & 63;
#pragma unroll
    for (int k = 0; k < 2; k++) {
        int e = active ? (k ? e1 : e0) : -1;
#pragma unroll
        for (int ex = 0; ex < NE; ex++) {
            u64 m = __ballot(e == ex);
            if (m && lane == 0) atomicAdd(&lcnt[ex], __popcll(m));
        }
    }
    __syncthreads();
    if (tid < NE && lcnt[tid]) atomicAdd(&counts[tid], lcnt[tid]);
}

// ---------------- padded prefix sum (pad to BM) ----------------
__global__ void offsets_kernel(const int* __restrict__ counts,
                               int* __restrict__ off,
                               int* __restrict__ cursor) {
    if (threadIdx.x == 0) {
        int acc = 0;
        for (int e = 0; e < NE; e++) {
            off[e] = acc;
            cursor[e] = acc;
            acc += (counts[e] + (BM - 1)) & ~(BM - 1);
        }
        off[NE] = acc;
    }
}

// ---------------- scatter: block/wave-aggregated ----------------
__global__ __launch_bounds__(RBLK) void scatter_kernel(
    int t0, int T,
    const int* __restrict__ eids,
    int* __restrict__ cursor,
    int* __restrict__ list_token,
    int* __restrict__ posl) {
    __shared__ int lcnt[NE], lbase[NE];
    __shared__ int woff[RBLK / 64][NE];
    int tid = threadIdx.x, lane = tid & 63, wv = tid >> 6;
    int i = blockIdx.x * RBLK + tid;
    bool active = (i < T);
    u64 lmask = (1ull << lane) - 1ull;

#pragma unroll
    for (int k = 0; k < 2; k++) {
        if (tid < NE) lcnt[tid] = 0;
        __syncthreads();
        int e = active ? eids[2 * i + k] : -1;
        u64 mymask = 0;
#pragma unroll
        for (int ex = 0; ex < NE; ex++) {
            u64 m = __ballot(e == ex);
            if (e == ex) mymask = m;
            if (m && lane == 0) woff[wv][ex] = atomicAdd(&lcnt[ex], __popcll(m));
        }
        __syncthreads();
        if (tid < NE) lbase[tid] = lcnt[tid] ? atomicAdd(&cursor[tid], lcnt[tid]) : 0;
        __syncthreads();
        if (active) {
            int p = lbase[e] + woff[wv][e] + __popcll(mymask & lmask);
            list_token[p] = t0 + i;
            posl[2 * i + k] = p;
        }
        __syncthreads();
    }
}

// ---------------- weight transpose + fp16 convert ----------------
// Wh[e][l][k][n] (l<3) / Wo[e][k][n]  ->  Wt[(e*4+l)][n][k] fp16
__global__ void convert_w(const float* __restrict__ Wh,
                          const float* __restrict__ Wo,
                          u16* __restrict__ Wt) {
    __shared__ float tile[32][33];
    int z = blockIdx.z;             // e*4 + l
    int e = z >> 2, l = z & 3;
    const float* src = (l < 3) ? (Wh + ((size_t)e * 3 + l) * DD * DD)
                               : (Wo + (size_t)e * DD * DD);
    int bx = blockIdx.x, by = blockIdx.y;
    int tx = threadIdx.x, ty = threadIdx.y; // 32 x 8
#pragma unroll
    for (int j = 0; j < 4; j++)
        tile[ty + j * 8][tx] = src[(size_t)(by * 32 + ty + j * 8) * DD + bx * 32 + tx];
    __syncthreads();
    u16* d = Wt + (size_t)z * DD * DD;
#pragma unroll
    for (int j = 0; j < 4; j++) {
        int n = bx * 32 + ty + j * 8;
        int k = by * 32 + tx;
        d[(size_t)n * DD + k] = f16bits(tile[tx][ty + j * 8]);
    }
}

// ---------------- fp16 MFMA GEMM: 128x128x32, 4 waves, wave-tile 64x64 ----------------
template <bool GATHER, bool RELU, bool OUTF32>
__global__ __launch_bounds__(256, 3) void moe_gemm(
    const float* __restrict__ Xf,
    const u16* __restrict__ Ain,          // fp16 activations (when !GATHER)
    const int* __restrict__ list_token,
    const u16* __restrict__ Wt,
    int layer,
    const float* __restrict__ bptr, int bestride,
    const int* __restrict__ off,
    u16* __restrict__ Ch,                 // fp16 output (when !OUTF32)
    float* __restrict__ Cf)
{
    // XCD-bijective swizzle (grid multiple of 8); cb-minor within XCD chunk
    u32 nb = gridDim.x, qq = nb >> 3, bid = blockIdx.x;
    u32 wg = (bid & 7) * qq + (bid >> 3);
    int rb = (int)(wg >> 2) * BM;
    if (rb >= off[NE]) return;
    int cb = (int)(wg & 3) * BN;
    int e = 0;
#pragma unroll
    for (int s = 1; s < NE; s++) if (rb >= off[s]) e = s;

    __shared__ u16 lds[8192];   // 16 KiB

    const int tid = threadIdx.x;
    const int lane = tid & 63, wv = tid >> 6;

    // staging: per array, thread covers chunks cc = j*256 + tid (j=0,1)
    // row = cc>>2, linear unit u = tid&3, swizzled logical unit us = u ^ ((row>>1)&3)
    int rowj[2], usj[2];
#pragma unroll
    for (int j = 0; j < 2; j++) {
        rowj[j] = j * 64 + (tid >> 2);
        usj[j]  = (tid & 3) ^ ((rowj[j] >> 1) & 3);
    }

    const size_t wbase = ((size_t)e * 4 + layer) * (size_t)DD * DD;
    const u16* bS[2];
    const u16* aS[2];
    const float* aF[2];
    int tokj[2] = {0, 0};
#pragma unroll
    for (int j = 0; j < 2; j++) {
        bS[j] = Wt + wbase + (size_t)(cb + rowj[j]) * DD + usj[j] * 8;
        if (GATHER) {
            tokj[j] = list_token[rb + rowj[j]];
            aF[j] = Xf + (size_t)(tokj[j] < 0 ? 0 : tokj[j]) * DD + usj[j] * 8;
        } else {
            aS[j] = Ain + (size_t)(rb + rowj[j]) * DD + usj[j] * 8;
        }
    }
    // wave-uniform LDS chunk bases (u16 idx): chunk (j*256 + wv*64), lane auto-offset x16B
    const int cb8[2] = { wv * 512, 2048 + wv * 512 };

    // MFMA read mapping: 2x2 wave grid, wave-tile 64x64
    const int r15 = lane & 15, lg = lane >> 4;
    const int wr = (wv >> 1) * 64, wc = (wv & 1) * 64;
    u32 aoff[4], boff[4];
#pragma unroll
    for (int i = 0; i < 4; i++) {
        int ar = wr + i * 16 + r15;
        aoff[i] = (u32)(ar * 32 + (lg ^ ((ar >> 1) & 3)) * 8);
        int br = wc + i * 16 + r15;
        boff[i] = (u32)(br * 32 + (lg ^ ((br >> 1) & 3)) * 8);
    }

    f32x4 acc[4][4];
#pragma unroll
    for (int i = 0; i < 4; i++)
#pragma unroll
        for (int j = 0; j < 4; j++) acc[i][j] = (f32x4){0.f, 0.f, 0.f, 0.f};

    for (int t = 0; t < NT; t++) {
        const int k0 = t * BK;
        // ---- stage tile t ----
#pragma unroll
        for (int j = 0; j < 2; j++)
            gl16(bS[j] + k0, &lds[OB + cb8[j]]);
        if (GATHER) {
#pragma unroll
            for (int j = 0; j < 2; j++) {
                const float4* fp = (const float4*)(aF[j] + k0);
                float4 f0 = fp[0], f1 = fp[1];
                if (tokj[j] < 0) { f0 = make_float4(0.f, 0.f, 0.f, 0.f); f1 = f0; }
                *(uint4*)&lds[OA + rowj[j] * 32 + (tid & 3) * 8] = pack_f16x8(f0, f1);
            }
        } else {
#pragma unroll
            for (int j = 0; j < 2; j++)
                gl16(aS[j] + k0, &lds[OA + cb8[j]]);
        }
        __syncthreads();

        // ---- compute: 8 ds_read_b128 + 16 MFMA per wave ----
        f16x8 a[4];
#pragma unroll
        for (int mi = 0; mi < 4; mi++)
            a[mi] = *(const f16x8*)&lds[OA + aoff[mi]];
#pragma unroll
        for (int ni = 0; ni < 4; ni++) {
            f16x8 b = *(const f16x8*)&lds[OB + boff[ni]];
#pragma unroll
            for (int mi = 0; mi < 4; mi++)
                acc[mi][ni] = __builtin_amdgcn_mfma_f32_16x16x32_f16(a[mi], b, acc[mi][ni], 0, 0, 0);
        }
        __syncthreads();
    }

    // ---- epilogue: bias (+relu); write fp32 or fp16 ----
#pragma unroll
    for (int ni = 0; ni < 4; ni++) {
        int col = cb + wc + ni * 16 + r15;
        float bbias = bptr[e * bestride + col];
#pragma unroll
        for (int mi = 0; mi < 4; mi++) {
            int row0 = rb + wr + mi * 16 + lg * 4;
#pragma unroll
            for (int rr = 0; rr < 4; rr++) {
                float v = acc[mi][ni][rr] + bbias;
                if (RELU) v = fmaxf(v, 0.f);
                size_t idx = (size_t)(row0 + rr) * DD + col;
                if (OUTF32) Cf[idx] = v;
                else        Ch[idx] = f16bits(v);
            }
        }
    }
}

// ---------------- combine ----------------
__global__ void combine_kernel(int t0, int T,
                               const float* __restrict__ y,
                               const int* __restrict__ posl,
                               const float* __restrict__ wts,
                               float* __restrict__ out) {
    int idx = blockIdx.x * blockDim.x + threadIdx.x;
    if (idx >= T * (DD / 4)) return;
    int i = idx >> 7;
    int j = idx & 127;
    int p0 = posl[2 * i], p1 = posl[2 * i + 1];
    float w0 = wts[2 * i], w1 = wts[2 * i + 1];
    float4 a = ((const float4*)(y + (size_t)p0 * DD))[j];
    float4 b = ((const float4*)(y + (size_t)p1 * DD))[j];
    float4 c;
    c.x = w0 * a.x + w1 * b.x;
    c.y = w0 * a.y + w1 * b.y;
    c.z = w0 * a.z + w1 * b.z;
    c.w = w0 * a.w + w1 * b.w;
    ((float4*)(out + (size_t)(t0 + i) * DD))[j] = c;
}

extern "C" void kernel_launch(void* const* d_in, const int* in_sizes, int n_in,
                              void* d_out, int out_size, void* d_ws, size_t ws_size,
                              hipStream_t stream) {
    const float* x  = (const float*)d_in[0];
    const float* Wg = (const float*)d_in[1];
    const float* bg = (const float*)d_in[2];
    const float* Wh = (const float*)d_in[3];
    const float* bh = (const float*)d_in[4];
    const float* Wo = (const float*)d_in[5];
    const float* bo = (const float*)d_in[6];
    float* out = (float*)d_out;

    const size_t WT_ELEMS = (size_t)NE * 4 * DD * DD;   // 8.39M fp16
    int T = NTOK;
    while (T > 64) {
        size_t C = 2 * (size_t)T + NE * BM;
        size_t need = 4096 + WT_ELEMS * 2 + 3 * ((size_t)T * 2 * 4)
                    + C * 4 + 512
                    + C * (size_t)DD * 2      // bufA fp16
                    + C * (size_t)DD * 4;     // regionB: bufB fp16 / yf fp32
        if (need <= ws_size) break;
        T >>= 1;
    }
    int phases = (NTOK + T - 1) / T;
    size_t C = 2 * (size_t)T + NE * BM;

    char* p = (char*)d_ws;
    int* counts = (int*)p;
    int* off    = (int*)(p + 64);
    int* cursor = (int*)(p + 128);
    char* q = p + 4096;
    u16* Wt = (u16*)q;    q += WT_ELEMS * 2;
    int* eids = (int*)q;  q += (size_t)T * 2 * 4;
    int* posl = (int*)q;  q += (size_t)T * 2 * 4;
    float* wts = (float*)q; q += (size_t)T * 2 * 4;
    int* list_token = (int*)q; q += C * 4;
    q = (char*)(((uintptr_t)q + 255) & ~(uintptr_t)255);
    u16* bufA = (u16*)q;  q += C * DD * 2;
    u16* bufB = (u16*)q;                       // aliases yf (fp32) below
    float* yf = (float*)bufB;                  // regionB: C*DD*4 bytes

    convert_w<<<dim3(16, 16, 32), dim3(32, 8), 0, stream>>>(Wh, Wo, Wt);

    for (int ph = 0; ph < phases; ph++) {
        int t0 = ph * T;
        int Tc = (NTOK - t0 < T) ? (NTOK - t0) : T;

        hipMemsetAsync(counts, 0, 256, stream);
        hipMemsetAsync(list_token, 0xFF, C * 4, stream);

        route_kernel<<<(Tc + RBLK - 1) / RBLK, RBLK, 0, stream>>>(
            x, Wg, bg, t0, Tc, counts, eids, wts);
        offsets_kernel<<<1, 64, 0, stream>>>(counts, off, cursor);
        scatter_kernel<<<(Tc + RBLK - 1) / RBLK, RBLK, 0, stream>>>(
            t0, Tc, eids, cursor, list_token, posl);

        // grid: (C/BM) row-panels x 4 col-blocks, 1-D, multiple of 8 for XCD swizzle
        unsigned NB = (unsigned)(C / BM) * (DD / BN);
        moe_gemm<true, true, false><<<NB, 256, 0, stream>>>(
            x, nullptr, list_token, Wt, 0,
            bh, 3 * DD, off, bufA, nullptr);
        moe_gemm<false, true, false><<<NB, 256, 0, stream>>>(
            nullptr, bufA, nullptr, Wt, 1,
            bh + DD, 3 * DD, off, bufB, nullptr);
        moe_gemm<false, true, false><<<NB, 256, 0, stream>>>(
            nullptr, bufB, nullptr, Wt, 2,
            bh + 2 * DD, 3 * DD, off, bufA, nullptr);
        moe_gemm<false, false, true><<<NB, 256, 0, stream>>>(
            nullptr, bufA, nullptr, Wt, 3,
            bo, DD, off, nullptr, yf);

        combine_kernel<<<((size_t)Tc * (DD / 4) + 255) / 256, 256, 0, stream>>>(
            t0, Tc, yf, posl, wts, out);
    }
}